// Round 1
// baseline (120.953 us; speedup 1.0000x reference)
//
#include <hip/hip_runtime.h>

#define T_DIM 1024
#define O_DIM 512
#define D_DIM 256
#define H_DIM 512

// ---------------- Kernel A: dual GEMM, transposed output into ws -----------
// Rows [0,16) of bm -> ht' = z_t @ W1[:D] + b1   stored as htT[h][t]  ([H][T])
// Rows [16,24)     -> ho  = z_o @ W1[D:]        stored as hoT[h][o]  ([H][O])
#define A_TM 64
#define A_TN 64
#define A_BK 16

__global__ __launch_bounds__(256) void gemm_a(
    const float* __restrict__ z_t, const float* __restrict__ z_o,
    const float* __restrict__ W1, const float* __restrict__ b1,
    float* __restrict__ ws)
{
    const int bm = blockIdx.x;
    const int bn = blockIdx.y;
    const bool is_o = bm >= (T_DIM / A_TM);
    const float* Amat = is_o ? z_o : z_t;
    const int m0 = (is_o ? bm - T_DIM / A_TM : bm) * A_TM;
    const int n0 = bn * A_TN;
    const int krow0 = is_o ? D_DIM : 0;
    const int Mdim = is_o ? O_DIM : T_DIM;
    float* outT = ws + (is_o ? (size_t)H_DIM * T_DIM : 0);

    __shared__ __align__(16) float a_s[A_BK][A_TM];  // [k][m]
    __shared__ __align__(16) float b_s[A_BK][A_TN];  // [k][n]

    const int tid = threadIdx.x;
    const int tx = tid & 15;   // n dir, 4 each
    const int ty = tid >> 4;   // m dir, 4 each

    float acc[4][4] = {};

    for (int k0 = 0; k0 < D_DIM; k0 += A_BK) {
        // stage A tile (64 m x 16 k), transposed into a_s[k][m]
        {
            const int m = tid >> 2;
            const int ks = (tid & 3) * 4;
            float4 v = *reinterpret_cast<const float4*>(
                &Amat[(size_t)(m0 + m) * D_DIM + k0 + ks]);
            a_s[ks + 0][m] = v.x;
            a_s[ks + 1][m] = v.y;
            a_s[ks + 2][m] = v.z;
            a_s[ks + 3][m] = v.w;
        }
        // stage B tile (16 k x 64 n), natural layout
        {
            const int k = tid >> 4;
            const int j = (tid & 15) * 4;
            *reinterpret_cast<float4*>(&b_s[k][j]) =
                *reinterpret_cast<const float4*>(
                    &W1[(size_t)(krow0 + k0 + k) * H_DIM + n0 + j]);
        }
        __syncthreads();
#pragma unroll
        for (int k = 0; k < A_BK; ++k) {
            float4 av = *reinterpret_cast<const float4*>(&a_s[k][ty * 4]);
            float4 bv = *reinterpret_cast<const float4*>(&b_s[k][tx * 4]);
            float a[4] = {av.x, av.y, av.z, av.w};
            float b[4] = {bv.x, bv.y, bv.z, bv.w};
#pragma unroll
            for (int i = 0; i < 4; ++i)
#pragma unroll
                for (int j = 0; j < 4; ++j)
                    acc[i][j] = fmaf(a[i], b[j], acc[i][j]);
        }
        __syncthreads();
    }

    // epilogue: transposed store outT[n][m0+4ty .. +3]; fold b1 into ht part
#pragma unroll
    for (int j = 0; j < 4; ++j) {
        const int n = n0 + tx * 4 + j;
        const float bias = is_o ? 0.0f : b1[n];
        float4 v = make_float4(acc[0][j] + bias, acc[1][j] + bias,
                               acc[2][j] + bias, acc[3][j] + bias);
        *reinterpret_cast<float4*>(&outT[(size_t)n * Mdim + m0 + ty * 4]) = v;
    }
}

// ---------------- Kernel B: fused broadcast-add + leaky + dot(W2) ----------
// out[t,o] = sum_h leaky(htT[h][t] + hoT[h][o]) * W2[h] + b2
#define B_BT 32
#define B_BO 64
#define B_HC 64
#define B_LT (B_BT + 4)   // 36: b64 reads 8B-aligned, b128 stores 16B-aligned
#define B_LO (B_BO + 4)   // 68

__global__ __launch_bounds__(256) void reduce_b(
    const float* __restrict__ ws, const float* __restrict__ W2,
    const float* __restrict__ b2, float* __restrict__ out)
{
    const float* htT = ws;                             // [H][T]
    const float* hoT = ws + (size_t)H_DIM * T_DIM;     // [H][O]

    const int bt = blockIdx.x * B_BT;
    const int bo = blockIdx.y * B_BO;

    __shared__ __align__(16) float ht_s[B_HC][B_LT];   // [h][t]
    __shared__ __align__(16) float ho_s[B_HC][B_LO];   // [h][o]
    __shared__ float w2_s[B_HC];

    const int tid = threadIdx.x;
    const int tx = tid & 15;   // o dir: owns o = bo + 4*tx .. +3
    const int ty = tid >> 4;   // t dir: owns t = bt + 2*ty .. +1

    float acc[2][4] = {};

    for (int h0 = 0; h0 < H_DIM; h0 += B_HC) {
        // stage ht chunk: 64 h x 32 t  (2 float4 per thread, coalesced rows)
        {
            int idx = tid;
#pragma unroll
            for (int r = 0; r < 2; ++r, idx += 256) {
                const int h = idx >> 3;
                const int t4 = (idx & 7) * 4;
                float4 v = *reinterpret_cast<const float4*>(
                    &htT[(size_t)(h0 + h) * T_DIM + bt + t4]);
                *reinterpret_cast<float4*>(&ht_s[h][t4]) = v;
            }
        }
        // stage ho chunk: 64 h x 64 o  (4 float4 per thread)
        {
            int idx = tid;
#pragma unroll
            for (int r = 0; r < 4; ++r, idx += 256) {
                const int h = idx >> 4;
                const int o4 = (idx & 15) * 4;
                float4 v = *reinterpret_cast<const float4*>(
                    &hoT[(size_t)(h0 + h) * O_DIM + bo + o4]);
                *reinterpret_cast<float4*>(&ho_s[h][o4]) = v;
            }
        }
        if (tid < B_HC / 4) {
            *reinterpret_cast<float4*>(&w2_s[tid * 4]) =
                *reinterpret_cast<const float4*>(&W2[h0 + tid * 4]);
        }
        __syncthreads();

#pragma unroll 8
        for (int h = 0; h < B_HC; ++h) {
            const float w = w2_s[h];                           // broadcast
            float2 a = *reinterpret_cast<const float2*>(&ht_s[h][ty * 2]);
            float4 b = *reinterpret_cast<const float4*>(&ho_s[h][tx * 4]);
            float av[2] = {a.x, a.y};
            float bv[4] = {b.x, b.y, b.z, b.w};
#pragma unroll
            for (int i = 0; i < 2; ++i)
#pragma unroll
                for (int j = 0; j < 4; ++j) {
                    const float s = av[i] + bv[j];
                    const float l = fmaxf(s, 0.01f * s);       // leaky_relu
                    acc[i][j] = fmaf(l, w, acc[i][j]);
                }
        }
        __syncthreads();
    }

    const float bias = b2[0];
#pragma unroll
    for (int i = 0; i < 2; ++i) {
        const int t = bt + ty * 2 + i;
        float4 v = make_float4(acc[i][0] + bias, acc[i][1] + bias,
                               acc[i][2] + bias, acc[i][3] + bias);
        *reinterpret_cast<float4*>(&out[(size_t)t * O_DIM + bo + tx * 4]) = v;
    }
}

extern "C" void kernel_launch(void* const* d_in, const int* in_sizes, int n_in,
                              void* d_out, int out_size, void* d_ws, size_t ws_size,
                              hipStream_t stream) {
    const float* z_t = (const float*)d_in[0];
    const float* z_o = (const float*)d_in[1];
    const float* W1  = (const float*)d_in[2];
    const float* b1  = (const float*)d_in[3];
    const float* W2  = (const float*)d_in[4];
    const float* b2  = (const float*)d_in[5];
    float* out = (float*)d_out;
    float* ws  = (float*)d_ws;   // htT [512][1024] then hoT [512][512] (3 MB)

    dim3 gridA((T_DIM + O_DIM) / A_TM, H_DIM / A_TN);   // (24, 8)
    gemm_a<<<gridA, 256, 0, stream>>>(z_t, z_o, W1, b1, ws);

    dim3 gridB(T_DIM / B_BT, O_DIM / B_BO);             // (32, 8)
    reduce_b<<<gridB, 256, 0, stream>>>(ws, W2, b2, out);
}

// Round 2
// 115.824 us; speedup vs baseline: 1.0443x; 1.0443x over previous
//
#include <hip/hip_runtime.h>
#include <cstdint>

#define T_DIM 1024
#define O_DIM 512
#define D_DIM 256
#define H_DIM 512
#define H2_DIM 256   // packed h-pairs

typedef _Float16 f16x2 __attribute__((ext_vector_type(2)));

__device__ __forceinline__ float fdot2f(f16x2 a, f16x2 b, float c) {
#if __has_builtin(__builtin_amdgcn_fdot2)
    return __builtin_amdgcn_fdot2(a, b, c, false);
#else
    return fmaf((float)a.x, (float)b.x, fmaf((float)a.y, (float)b.y, c));
#endif
}

// ---------------- Kernel A: dual GEMM -> packed-f16 transposed ws ----------
// htT2[h2][t] = pack_f16(ht[2h2][t]+b1, ht[2h2+1][t]+b1)   [H2][T]
// hoT2[h2][o] = pack_f16(ho[2h2][o],    ho[2h2+1][o])      [H2][O]
#define A_TM 64
#define A_TN 64
#define A_BK 16

__global__ __launch_bounds__(256) void gemm_a(
    const float* __restrict__ z_t, const float* __restrict__ z_o,
    const float* __restrict__ W1, const float* __restrict__ b1,
    uint32_t* __restrict__ htT2, uint32_t* __restrict__ hoT2)
{
    const int bm = blockIdx.x;
    const int bn = blockIdx.y;
    const bool is_o = bm >= (T_DIM / A_TM);
    const float* Amat = is_o ? z_o : z_t;
    const int m0 = (is_o ? bm - T_DIM / A_TM : bm) * A_TM;
    const int n0 = bn * A_TN;
    const int krow0 = is_o ? D_DIM : 0;
    const int Mdim = is_o ? O_DIM : T_DIM;
    uint32_t* outT2 = is_o ? hoT2 : htT2;

    __shared__ __align__(16) float a_s[A_BK][A_TM];  // [k][m]
    __shared__ __align__(16) float b_s[A_BK][A_TN];  // [k][n]

    const int tid = threadIdx.x;
    const int tx = tid & 15;   // n dir, 4 each
    const int ty = tid >> 4;   // m dir, 4 each

    float acc[4][4] = {};

    for (int k0 = 0; k0 < D_DIM; k0 += A_BK) {
        {
            const int m = tid >> 2;
            const int ks = (tid & 3) * 4;
            float4 v = *reinterpret_cast<const float4*>(
                &Amat[(size_t)(m0 + m) * D_DIM + k0 + ks]);
            a_s[ks + 0][m] = v.x;
            a_s[ks + 1][m] = v.y;
            a_s[ks + 2][m] = v.z;
            a_s[ks + 3][m] = v.w;
        }
        {
            const int k = tid >> 4;
            const int j = (tid & 15) * 4;
            *reinterpret_cast<float4*>(&b_s[k][j]) =
                *reinterpret_cast<const float4*>(
                    &W1[(size_t)(krow0 + k0 + k) * H_DIM + n0 + j]);
        }
        __syncthreads();
#pragma unroll
        for (int k = 0; k < A_BK; ++k) {
            float4 av = *reinterpret_cast<const float4*>(&a_s[k][ty * 4]);
            float4 bv = *reinterpret_cast<const float4*>(&b_s[k][tx * 4]);
            float a[4] = {av.x, av.y, av.z, av.w};
            float b[4] = {bv.x, bv.y, bv.z, bv.w};
#pragma unroll
            for (int i = 0; i < 4; ++i)
#pragma unroll
                for (int j = 0; j < 4; ++j)
                    acc[i][j] = fmaf(a[i], b[j], acc[i][j]);
        }
        __syncthreads();
    }

    // epilogue: fold b1 (ht only), round to f16 pairs, transposed b128 store
    const int h0 = n0 + tx * 4;
    float bias[4];
#pragma unroll
    for (int j = 0; j < 4; ++j) bias[j] = is_o ? 0.0f : b1[h0 + j];

#pragma unroll
    for (int jp = 0; jp < 2; ++jp) {
        uint32_t vals[4];
#pragma unroll
        for (int i = 0; i < 4; ++i) {
            f16x2 p;
            p.x = (_Float16)(acc[i][2 * jp + 0] + bias[2 * jp + 0]);
            p.y = (_Float16)(acc[i][2 * jp + 1] + bias[2 * jp + 1]);
            vals[i] = __builtin_bit_cast(uint32_t, p);
        }
        uint4 v = make_uint4(vals[0], vals[1], vals[2], vals[3]);
        *reinterpret_cast<uint4*>(
            &outT2[(size_t)(h0 / 2 + jp) * Mdim + m0 + ty * 4]) = v;
    }
}

// ---------------- Kernel B: separable rank-1 terms ct[t], co[o] ------------
// ct[t] = sum_h W2[h]*ht[t,h] (b1 folded), co[o] = sum_h W2[h]*ho[o,h]
__global__ __launch_bounds__(256) void ctco(
    const uint32_t* __restrict__ htT2, const uint32_t* __restrict__ hoT2,
    const float* __restrict__ W2, float* __restrict__ ct, float* __restrict__ co)
{
    const int b = blockIdx.x;
    const int tid = threadIdx.x;
    const uint32_t* src;
    int stride, idx;
    float* dst;
    if (b < 4) { idx = b * 256 + tid; src = htT2; stride = T_DIM; dst = ct + idx; }
    else       { idx = (b - 4) * 256 + tid; src = hoT2; stride = O_DIM; dst = co + idx; }

    float acc = 0.0f;
#pragma unroll 8
    for (int h2 = 0; h2 < H2_DIM; ++h2) {
        f16x2 hv = __builtin_bit_cast(f16x2, src[(size_t)h2 * stride + idx]);
        acc = fmaf((float)hv.x, W2[2 * h2 + 0], acc);
        acc = fmaf((float)hv.y, W2[2 * h2 + 1], acc);
    }
    *dst = acc;
}

// ---------------- Kernel C: abs-part reduction, h-split partials -----------
// part[hs][t][o] = sum_{h in chunk hs} W2[h] * |ht[t,h]+ho[o,h]|
#define R_HC 64   // h2 pairs per block (=128 h), H2/R_HC = 4 splits

__global__ __launch_bounds__(256) void reduce_b(
    const uint32_t* __restrict__ htT2, const uint32_t* __restrict__ hoT2,
    const float* __restrict__ W2, float* __restrict__ part)
{
    __shared__ __align__(16) uint32_t ht_s[R_HC * 64];  // [h2][t]
    __shared__ __align__(16) uint32_t ho_s[R_HC * 64];  // [h2][o]

    const int tid = threadIdx.x;
    const int t0 = blockIdx.x * 64;
    const int o0 = blockIdx.y * 64;
    const int h2b = blockIdx.z * R_HC;

    // stage 16KB + 16KB, uint4 coalesced (rows of 64 uint32 = 16 uint4)
#pragma unroll
    for (int r = 0; r < 4; ++r) {
        const int c = tid + r * 256;
        const int row = c >> 4;
        const int c4 = (c & 15) * 4;
        *reinterpret_cast<uint4*>(&ht_s[row * 64 + c4]) =
            *reinterpret_cast<const uint4*>(&htT2[(size_t)(h2b + row) * T_DIM + t0 + c4]);
        *reinterpret_cast<uint4*>(&ho_s[row * 64 + c4]) =
            *reinterpret_cast<const uint4*>(&hoT2[(size_t)(h2b + row) * O_DIM + o0 + c4]);
    }
    __syncthreads();

    const int tx = tid & 15;   // o dir, 4 each
    const int ty = tid >> 4;   // t dir, 4 each

    float acc[4][4] = {};

#pragma unroll 4
    for (int h2 = 0; h2 < R_HC; ++h2) {
        f16x2 w;
        w.x = (_Float16)W2[(h2b + h2) * 2 + 0];
        w.y = (_Float16)W2[(h2b + h2) * 2 + 1];
        uint4 a = *reinterpret_cast<const uint4*>(&ht_s[h2 * 64 + ty * 4]);
        uint4 b = *reinterpret_cast<const uint4*>(&ho_s[h2 * 64 + tx * 4]);
        uint32_t av[4] = {a.x, a.y, a.z, a.w};
        uint32_t bv[4] = {b.x, b.y, b.z, b.w};
#pragma unroll
        for (int i = 0; i < 4; ++i)
#pragma unroll
            for (int j = 0; j < 4; ++j) {
                f16x2 s = __builtin_bit_cast(f16x2, av[i]) +
                          __builtin_bit_cast(f16x2, bv[j]);          // v_pk_add_f16
                uint32_t su = __builtin_bit_cast(uint32_t, s) & 0x7FFF7FFFu;  // |.|
                acc[i][j] = fdot2f(__builtin_bit_cast(f16x2, su), w, acc[i][j]);
            }
    }

    float* p = part + (size_t)blockIdx.z * T_DIM * O_DIM;
#pragma unroll
    for (int i = 0; i < 4; ++i) {
        float4 v = make_float4(acc[i][0], acc[i][1], acc[i][2], acc[i][3]);
        *reinterpret_cast<float4*>(
            &p[(size_t)(t0 + ty * 4 + i) * O_DIM + o0 + tx * 4]) = v;
    }
}

// ---------------- Kernel D: combine --------------------------------------
// out = b2 + 0.505*(ct+co) + 0.495*sum_hs part
__global__ __launch_bounds__(256) void combine(
    const float* __restrict__ part, const float* __restrict__ ct,
    const float* __restrict__ co, const float* __restrict__ b2,
    float* __restrict__ out)
{
    const float bb = b2[0];
    const int Q = T_DIM * O_DIM / 4;   // float4 count per partial
#pragma unroll
    for (int r = 0; r < 2; ++r) {
        const int idx = blockIdx.x * 512 + r * 256 + threadIdx.x;  // float4 idx
        const int o4 = idx & (O_DIM / 4 - 1);
        const int t = idx >> 7;
        const float4* p = reinterpret_cast<const float4*>(part);
        float4 s0 = p[idx];
        float4 s1 = p[idx + Q];
        float4 s2 = p[idx + 2 * Q];
        float4 s3 = p[idx + 3 * Q];
        float4 cov = reinterpret_cast<const float4*>(co)[o4];
        const float base = bb + 0.505f * ct[t];
        float4 o;
        o.x = base + 0.505f * cov.x + 0.495f * (s0.x + s1.x + s2.x + s3.x);
        o.y = base + 0.505f * cov.y + 0.495f * (s0.y + s1.y + s2.y + s3.y);
        o.z = base + 0.505f * cov.z + 0.495f * (s0.z + s1.z + s2.z + s3.z);
        o.w = base + 0.505f * cov.w + 0.495f * (s0.w + s1.w + s2.w + s3.w);
        reinterpret_cast<float4*>(out)[idx] = o;
    }
}

extern "C" void kernel_launch(void* const* d_in, const int* in_sizes, int n_in,
                              void* d_out, int out_size, void* d_ws, size_t ws_size,
                              hipStream_t stream) {
    const float* z_t = (const float*)d_in[0];
    const float* z_o = (const float*)d_in[1];
    const float* W1  = (const float*)d_in[2];
    const float* b1  = (const float*)d_in[3];
    const float* W2  = (const float*)d_in[4];
    const float* b2  = (const float*)d_in[5];
    float* out = (float*)d_out;

    // ws layout: htT2 1MB | hoT2 0.5MB | ct 4KB | co 2KB | part 8MB @ 2MB
    char* wsb = (char*)d_ws;
    uint32_t* htT2 = (uint32_t*)(wsb);
    uint32_t* hoT2 = (uint32_t*)(wsb + (1u << 20));
    float* ct      = (float*)(wsb + 0x180000);
    float* co      = (float*)(wsb + 0x181000);
    float* part    = (float*)(wsb + 0x200000);

    dim3 gridA((T_DIM + O_DIM) / A_TM, H_DIM / A_TN);   // (24, 8)
    gemm_a<<<gridA, 256, 0, stream>>>(z_t, z_o, W1, b1, htT2, hoT2);

    ctco<<<6, 256, 0, stream>>>(htT2, hoT2, W2, ct, co);

    dim3 gridB(T_DIM / 64, O_DIM / 64, H2_DIM / R_HC);  // (16, 8, 4)
    reduce_b<<<gridB, 256, 0, stream>>>(htT2, hoT2, W2, part);

    combine<<<T_DIM * O_DIM / (4 * 512), 256, 0, stream>>>(part, ct, co, b2, out);
}

// Round 4
// 95.671 us; speedup vs baseline: 1.2643x; 1.2106x over previous
//
#include <hip/hip_runtime.h>
#include <cstdint>

#define T_DIM 1024
#define O_DIM 512
#define D_DIM 256
#define H_DIM 512
#define H2_DIM 256   // packed h-pairs

typedef _Float16 f16x2 __attribute__((ext_vector_type(2)));
typedef _Float16 f16x8 __attribute__((ext_vector_type(8)));
typedef float f32x4 __attribute__((ext_vector_type(4)));

__device__ __forceinline__ float fdot2f(f16x2 a, f16x2 b, float c) {
#if __has_builtin(__builtin_amdgcn_fdot2)
    return __builtin_amdgcn_fdot2(a, b, c, false);
#else
    return fmaf((float)a.x, (float)b.x, fmaf((float)a.y, (float)b.y, c));
#endif
}

__device__ __forceinline__ uint32_t pack2(float a, float b) {
    f16x2 p;
    p.x = (_Float16)a;
    p.y = (_Float16)b;
    return __builtin_bit_cast(uint32_t, p);
}

struct u4 { uint32_t x, y, z, w; };

// ---------------- Kernel A: MFMA f16 dual GEMM -> packed transposed ws -----
// Computes D'[n][m] = sum_k W1[k][n]*Amat[m][k] (+b1 for ht), written as
// outT2[h2=n/2][m] = f16pair(n, n+1).  C/D layout: col(lane&15)=m,
// row(quad*4+reg)=n -> 4 regs = 4 consecutive n = two h-pairs in-lane.
#define GA_PAD 20   // uint32 (f16-pair) row stride: 16 kp + 4 pad (2-way only)

__global__ __launch_bounds__(256) void gemm_a(
    const float* __restrict__ z_t, const float* __restrict__ z_o,
    const float* __restrict__ W1, const float* __restrict__ b1,
    uint32_t* __restrict__ htT2, uint32_t* __restrict__ hoT2)
{
    const int bm = blockIdx.x;
    const int bn = blockIdx.y;
    const bool is_o = bm >= (T_DIM / 64);
    const float* Amat = is_o ? z_o : z_t;
    const int m0 = (is_o ? bm - T_DIM / 64 : bm) * 64;
    const int n0 = bn * 64;
    const int krow0 = is_o ? D_DIM : 0;
    const int Mdim = is_o ? O_DIM : T_DIM;
    uint32_t* outT2 = is_o ? hoT2 : htT2;

    __shared__ __align__(16) uint32_t lds_a[64 * GA_PAD];  // [m][kp] f16 pairs
    __shared__ __align__(16) uint32_t lds_w[64 * GA_PAD];  // [n][kp] f16 pairs

    const int tid = threadIdx.x;
    const int lane = tid & 63;
    const int wv = tid >> 6;       // wave id 0..3 -> n-slice
    const int quad = lane >> 4;
    const int l15 = lane & 15;

    f32x4 acc[4];
#pragma unroll
    for (int i = 0; i < 4; ++i) acc[i] = (f32x4)(0.0f);

    const int a_m = tid >> 2;
    const int a_kq = (tid & 3) * 8;
    const int w_kp = tid >> 4;
    const int w_nq = (tid & 15) * 4;

    for (int k0 = 0; k0 < D_DIM; k0 += 32) {
        // stage Amat tile 64m x 32k -> lds_a[m][kp]
        {
            const float* p = &Amat[(size_t)(m0 + a_m) * D_DIM + k0 + a_kq];
            float4 v0 = *reinterpret_cast<const float4*>(p);
            float4 v1 = *reinterpret_cast<const float4*>(p + 4);
            lds_a[a_m * GA_PAD + a_kq / 2 + 0] = pack2(v0.x, v0.y);
            lds_a[a_m * GA_PAD + a_kq / 2 + 1] = pack2(v0.z, v0.w);
            lds_a[a_m * GA_PAD + a_kq / 2 + 2] = pack2(v1.x, v1.y);
            lds_a[a_m * GA_PAD + a_kq / 2 + 3] = pack2(v1.z, v1.w);
        }
        // stage W1 tile 32k x 64n transposed -> lds_w[n][kp]
        {
            const float* r0 = &W1[(size_t)(krow0 + k0 + 2 * w_kp) * H_DIM + n0 + w_nq];
            float4 a0 = *reinterpret_cast<const float4*>(r0);
            float4 a1 = *reinterpret_cast<const float4*>(r0 + H_DIM);
            lds_w[(w_nq + 0) * GA_PAD + w_kp] = pack2(a0.x, a1.x);
            lds_w[(w_nq + 1) * GA_PAD + w_kp] = pack2(a0.y, a1.y);
            lds_w[(w_nq + 2) * GA_PAD + w_kp] = pack2(a0.z, a1.z);
            lds_w[(w_nq + 3) * GA_PAD + w_kp] = pack2(a0.w, a1.w);
        }
        __syncthreads();

        // A-frag: W1^T row n = wv*16+l15, k = quad*8..+7 (4 dwords)
        u4 au;
        {
            const uint32_t* s = &lds_w[(wv * 16 + l15) * GA_PAD + quad * 4];
            au.x = s[0]; au.y = s[1]; au.z = s[2]; au.w = s[3];
        }
        f16x8 afrag = __builtin_bit_cast(f16x8, au);
#pragma unroll
        for (int mi = 0; mi < 4; ++mi) {
            u4 bu;
            const uint32_t* s = &lds_a[(mi * 16 + l15) * GA_PAD + quad * 4];
            bu.x = s[0]; bu.y = s[1]; bu.z = s[2]; bu.w = s[3];
            f16x8 bfrag = __builtin_bit_cast(f16x8, bu);
            acc[mi] = __builtin_amdgcn_mfma_f32_16x16x32_f16(afrag, bfrag,
                                                             acc[mi], 0, 0, 0);
        }
        __syncthreads();
    }

    // epilogue: rows n = nbase..+3 in regs; pack pairs, fold b1
    const int nbase = n0 + wv * 16 + quad * 4;
    float b0 = 0.f, b1v = 0.f, b2v = 0.f, b3v = 0.f;
    if (!is_o) {
        b0 = b1[nbase + 0]; b1v = b1[nbase + 1];
        b2v = b1[nbase + 2]; b3v = b1[nbase + 3];
    }
#pragma unroll
    for (int mi = 0; mi < 4; ++mi) {
        const int m = m0 + mi * 16 + l15;
        outT2[(size_t)((nbase >> 1) + 0) * Mdim + m] = pack2(acc[mi][0] + b0, acc[mi][1] + b1v);
        outT2[(size_t)((nbase >> 1) + 1) * Mdim + m] = pack2(acc[mi][2] + b2v, acc[mi][3] + b3v);
    }
}

// ---------------- Kernel B: separable rank-1 terms ct[t], co[o] ------------
// 24 blocks: 64 outputs each, 4 h-chunks (one per wave), LDS combine.
__global__ __launch_bounds__(256) void ctco(
    const uint32_t* __restrict__ htT2, const uint32_t* __restrict__ hoT2,
    const float* __restrict__ W2, float* __restrict__ ct, float* __restrict__ co)
{
    __shared__ uint32_t w2s[H2_DIM];
    __shared__ float red[4][64];
    const int tid = threadIdx.x;
    w2s[tid] = pack2(W2[2 * tid], W2[2 * tid + 1]);
    __syncthreads();

    const int b = blockIdx.x;
    const int g = tid & 63;
    const int c = tid >> 6;
    const uint32_t* src;
    int stride, base;
    float* dst;
    if (b < 16) { base = b * 64; src = htT2; stride = T_DIM; dst = ct; }
    else        { base = (b - 16) * 64; src = hoT2; stride = O_DIM; dst = co; }
    const int idx = base + g;

    float acc = 0.0f;
#pragma unroll 8
    for (int i = 0; i < 64; ++i) {
        const int h2 = c * 64 + i;
        f16x2 hv = __builtin_bit_cast(f16x2, src[(size_t)h2 * stride + idx]);
        acc = fdot2f(hv, __builtin_bit_cast(f16x2, w2s[h2]), acc);
    }
    red[c][g] = acc;
    __syncthreads();
    if (tid < 64)
        dst[base + tid] = red[0][tid] + red[1][tid] + red[2][tid] + red[3][tid];
}

// ---------------- Kernel C: abs-part reduction, h-split partials -----------
// part[hs][t][o] = sum_{h in chunk} W2[h] * |ht[t,h]+ho[o,h]|
#define R_HC 64   // h2 pairs per block (=128 h), 4 splits

__global__ __launch_bounds__(256) void reduce_b(
    const uint32_t* __restrict__ htT2, const uint32_t* __restrict__ hoT2,
    const float* __restrict__ W2, float* __restrict__ part)
{
    __shared__ __align__(16) uint32_t ht_s[R_HC * 64];  // [h2][t]
    __shared__ __align__(16) uint32_t ho_s[R_HC * 64];  // [h2][o]
    __shared__ uint32_t w2s[R_HC];

    const int tid = threadIdx.x;
    const int t0 = blockIdx.x * 64;
    const int o0 = blockIdx.y * 64;
    const int h2b = blockIdx.z * R_HC;

    if (tid < R_HC)
        w2s[tid] = pack2(W2[(h2b + tid) * 2], W2[(h2b + tid) * 2 + 1]);

#pragma unroll
    for (int r = 0; r < 4; ++r) {
        const int c = tid + r * 256;
        const int row = c >> 4;
        const int c4 = (c & 15) * 4;
        *reinterpret_cast<uint4*>(&ht_s[row * 64 + c4]) =
            *reinterpret_cast<const uint4*>(&htT2[(size_t)(h2b + row) * T_DIM + t0 + c4]);
        *reinterpret_cast<uint4*>(&ho_s[row * 64 + c4]) =
            *reinterpret_cast<const uint4*>(&hoT2[(size_t)(h2b + row) * O_DIM + o0 + c4]);
    }
    __syncthreads();

    const int tx = tid & 15;   // o dir, 4 each
    const int ty = tid >> 4;   // t dir, 4 each

    float acc[4][4] = {};

#pragma unroll 4
    for (int h2 = 0; h2 < R_HC; ++h2) {
        f16x2 w = __builtin_bit_cast(f16x2, w2s[h2]);
        uint4 a = *reinterpret_cast<const uint4*>(&ht_s[h2 * 64 + ty * 4]);
        uint4 b = *reinterpret_cast<const uint4*>(&ho_s[h2 * 64 + tx * 4]);
        uint32_t av[4] = {a.x, a.y, a.z, a.w};
        uint32_t bv[4] = {b.x, b.y, b.z, b.w};
#pragma unroll
        for (int i = 0; i < 4; ++i)
#pragma unroll
            for (int j = 0; j < 4; ++j) {
                f16x2 s = __builtin_bit_cast(f16x2, av[i]) +
                          __builtin_bit_cast(f16x2, bv[j]);            // pk_add
                uint32_t su = __builtin_bit_cast(uint32_t, s) & 0x7FFF7FFFu;
                acc[i][j] = fdot2f(__builtin_bit_cast(f16x2, su), w, acc[i][j]);
            }
    }

    float* p = part + (size_t)blockIdx.z * T_DIM * O_DIM;
#pragma unroll
    for (int i = 0; i < 4; ++i) {
        float4 v = make_float4(acc[i][0], acc[i][1], acc[i][2], acc[i][3]);
        *reinterpret_cast<float4*>(
            &p[(size_t)(t0 + ty * 4 + i) * O_DIM + o0 + tx * 4]) = v;
    }
}

// ---------------- Kernel D: combine ----------------------------------------
// out = b2 + 0.505*(ct+co) + 0.495*sum_hs part
__global__ __launch_bounds__(256) void combine(
    const float* __restrict__ part, const float* __restrict__ ct,
    const float* __restrict__ co, const float* __restrict__ b2,
    float* __restrict__ out)
{
    const float bb = b2[0];
    const int Q = T_DIM * O_DIM / 4;
#pragma unroll
    for (int r = 0; r < 2; ++r) {
        const int idx = blockIdx.x * 512 + r * 256 + threadIdx.x;
        const int o4 = idx & (O_DIM / 4 - 1);
        const int t = idx >> 7;
        const float4* p = reinterpret_cast<const float4*>(part);
        float4 s0 = p[idx];
        float4 s1 = p[idx + Q];
        float4 s2 = p[idx + 2 * Q];
        float4 s3 = p[idx + 3 * Q];
        float4 cov = reinterpret_cast<const float4*>(co)[o4];
        const float base = bb + 0.505f * ct[t];
        float4 o;
        o.x = base + 0.505f * cov.x + 0.495f * (s0.x + s1.x + s2.x + s3.x);
        o.y = base + 0.505f * cov.y + 0.495f * (s0.y + s1.y + s2.y + s3.y);
        o.z = base + 0.505f * cov.z + 0.495f * (s0.z + s1.z + s2.z + s3.z);
        o.w = base + 0.505f * cov.w + 0.495f * (s0.w + s1.w + s2.w + s3.w);
        reinterpret_cast<float4*>(out)[idx] = o;
    }
}

extern "C" void kernel_launch(void* const* d_in, const int* in_sizes, int n_in,
                              void* d_out, int out_size, void* d_ws, size_t ws_size,
                              hipStream_t stream) {
    const float* z_t = (const float*)d_in[0];
    const float* z_o = (const float*)d_in[1];
    const float* W1  = (const float*)d_in[2];
    const float* b1  = (const float*)d_in[3];
    const float* W2  = (const float*)d_in[4];
    const float* b2  = (const float*)d_in[5];
    float* out = (float*)d_out;

    // ws layout: htT2 1MB | hoT2 0.5MB | ct 4KB | co 2KB | part 8MB @ 2MB
    char* wsb = (char*)d_ws;
    uint32_t* htT2 = (uint32_t*)(wsb);
    uint32_t* hoT2 = (uint32_t*)(wsb + (1u << 20));
    float* ct      = (float*)(wsb + 0x180000);
    float* co      = (float*)(wsb + 0x181000);
    float* part    = (float*)(wsb + 0x200000);

    dim3 gridA((T_DIM + O_DIM) / 64, H_DIM / 64);       // (24, 8)
    gemm_a<<<gridA, 256, 0, stream>>>(z_t, z_o, W1, b1, htT2, hoT2);

    ctco<<<24, 256, 0, stream>>>(htT2, hoT2, W2, ct, co);

    dim3 gridB(T_DIM / 64, O_DIM / 64, H2_DIM / R_HC);  // (16, 8, 4)
    reduce_b<<<gridB, 256, 0, stream>>>(htT2, hoT2, W2, part);

    combine<<<T_DIM * O_DIM / (4 * 512), 256, 0, stream>>>(part, ct, co, b2, out);
}